// Round 8
// baseline (13565.248 us; speedup 1.0000x reference)
//
#include <hip/hip_runtime.h>
#include <math.h>

#define NN   16384      // total nodes
#define NE   262144     // edges (no self loops)
#define NB   64         // graphs
#define SEQT 256        // nodes per graph (= seq len)
#define DEP  64
#define DOUT 256        // = HID
#define G3   768        // 3*HID
#define ECAP 64         // GCN edges staged per chunk

typedef _Float16 h2_t   __attribute__((ext_vector_type(2)));
typedef _Float16 f16x4  __attribute__((ext_vector_type(4)));
typedef _Float16 f16x8  __attribute__((ext_vector_type(8)));
typedef float    f32x4  __attribute__((ext_vector_type(4)));

static __device__ __forceinline__ h2_t pk(float a, float b) {
    return (h2_t)__builtin_amdgcn_cvt_pkrtz(a, b);
}

static __device__ __forceinline__ float fast_sigmoid(float v) {
    return __builtin_amdgcn_rcpf(1.f + __expf(-v));
}
static __device__ __forceinline__ float fast_tanh(float v) {
    return 1.f - 2.f * __builtin_amdgcn_rcpf(1.f + __expf(2.f * v));
}

// barrier with LDS-only drain (no vmcnt: in-flight global loads/stores cross)
static __device__ __forceinline__ void bar_lds() {
    asm volatile("s_waitcnt lgkmcnt(0)\n\ts_barrier" ::: "memory");
}

// ---------------------------------------------------------------------------
// degree / CSR build (deg zero-initialized by memset; holds RAW in-degree)
// ---------------------------------------------------------------------------
__global__ void k_count(const int* __restrict__ ei, int* deg) {
    int e = blockIdx.x * 256 + threadIdx.x;
    if (e < NE) atomicAdd(&deg[ei[NE + e]], 1);   // col = dst
}

__global__ __launch_bounds__(1024) void k_scan_offs(const int* __restrict__ deg,
                                                    int* __restrict__ offs,
                                                    float* __restrict__ dinv) {
    __shared__ int lds[1024];
    const int tid = threadIdx.x;
    const int v0 = tid * 16;
    int loc[16];
    int s = 0;
#pragma unroll
    for (int i = 0; i < 16; ++i) {
        int d = deg[v0 + i];                      // raw in-edges
        loc[i] = s;
        s += d;
        dinv[v0 + i] = rsqrtf((float)(d + 1));    // +1 self loop
    }
    lds[tid] = s;
    __syncthreads();
    for (int off = 1; off < 1024; off <<= 1) {
        int x = (tid >= off) ? lds[tid - off] : 0;
        __syncthreads();
        lds[tid] += x;
        __syncthreads();
    }
    int base = lds[tid] - s;                      // exclusive prefix of this thread
#pragma unroll
    for (int i = 0; i < 16; ++i) offs[v0 + i] = base + loc[i];
}

__global__ void k_fill(const int* __restrict__ ei, const int* __restrict__ offs,
                       int* cursor, int* __restrict__ eidx) {
    int e = blockIdx.x * 256 + threadIdx.x;
    if (e < NE) {
        int c = ei[NE + e];
        int pos = offs[c] + atomicAdd(&cursor[c], 1);
        eidx[pos] = e;
    }
}

// merged setup: block 0 -> Bself (rowsum of WB); blocks 1..9 -> bias fold.
// bias768[l][j] = b_ih[j] + (j<512 ? b_hh[j] : 0)  (b_hn stays separate)
__global__ void k_prep(const float* __restrict__ WB, float* __restrict__ Bself,
                       const float* __restrict__ bi0, const float* __restrict__ bh0,
                       const float* __restrict__ bi1, const float* __restrict__ bh1,
                       const float* __restrict__ bi2, const float* __restrict__ bh2,
                       float* __restrict__ o) {
    if (blockIdx.x == 0) {
        int f = threadIdx.x;                      // 256 threads
        float s = 0.f;
#pragma unroll
        for (int d = 0; d < DEP; ++d) s += WB[f * DEP + d];
        Bself[f] = s;
        return;
    }
    int j = (blockIdx.x - 1) * 256 + threadIdx.x; // 9 blocks x 256 = 2304
    int l = j / G3, r = j % G3;
    const float* bi = (l == 0) ? bi0 : (l == 1) ? bi1 : bi2;
    const float* bh = (l == 0) ? bh0 : (l == 1) ? bh1 : bh2;
    o[j] = bi[r] + (r < 512 ? bh[r] : 0.f);
}

// ---------------------------------------------------------------------------
// one fused fp32->f16 conversion over all 7 regions
// (x, WA, w_ih0/1/2, edge_attr, WB)
// ---------------------------------------------------------------------------
__global__ void k_cvt_all(const float* __restrict__ x,  const float* __restrict__ wa,
                          const float* __restrict__ w0, const float* __restrict__ w1,
                          const float* __restrict__ w2, const float* __restrict__ ea,
                          const float* __restrict__ wb,
                          _Float16* __restrict__ xo,  _Float16* __restrict__ wao,
                          _Float16* __restrict__ w0o, _Float16* __restrict__ w1o,
                          _Float16* __restrict__ w2o, _Float16* __restrict__ eao,
                          _Float16* __restrict__ wbo) {
    size_t i = ((size_t)blockIdx.x * 256 + threadIdx.x) * 4;
    const size_t B0 = 4194304;                  // x: NN*256
    const size_t B1 = B0 + 65536;               // WA: 256*256
    const size_t B2 = B1 + 196608;              // w_ih0: 768*256
    const size_t B3 = B2 + 196608;              // w_ih1
    const size_t B4 = B3 + 196608;              // w_ih2
    const size_t B5 = B4 + 16777216;            // edge_attr: NE*64
    const float* in; _Float16* out; size_t off;
    if      (i < B0) { in = x;  out = xo;  off = i; }
    else if (i < B1) { in = wa; out = wao; off = i - B0; }
    else if (i < B2) { in = w0; out = w0o; off = i - B1; }
    else if (i < B3) { in = w1; out = w1o; off = i - B2; }
    else if (i < B4) { in = w2; out = w2o; off = i - B3; }
    else if (i < B5) { in = ea; out = eao; off = i - B4; }
    else             { in = wb; out = wbo; off = i - B5; }
    float4 v = *(const float4*)(in + off);
    *(h2_t*)(out + off)     = pk(v.x, v.y);
    *(h2_t*)(out + off + 2) = pk(v.z, v.w);
}

// ---------------------------------------------------------------------------
// MFMA f16 GEMM: C[M,N] = A16[M,K] @ B16[N,K]^T (+ bias).
// K: 256 (node GEMMs) or 64 (edge Be GEMM). F16OUT: f16 store, else fp32.
// ---------------------------------------------------------------------------
template <int K, bool F16OUT>
__global__ __launch_bounds__(256) void k_gemm16(const _Float16* __restrict__ A16,
                                                const _Float16* __restrict__ B16,
                                                const float* __restrict__ bias,
                                                void* __restrict__ Cout,
                                                int M, int N) {
    const int tid  = threadIdx.x;
    const int lane = tid & 63;
    const int wv   = tid >> 6;
    const int m0   = blockIdx.x * 128 + wv * 32;
    const int n0   = blockIdx.y * 128;
    const int ml   = lane & 15;
    const int quad = lane >> 4;

    const _Float16* ap0 = A16 + (size_t)(m0 + ml) * K + quad * 8;
    const _Float16* ap1 = ap0 + (size_t)16 * K;
    const _Float16* bp0 = B16 + (size_t)(n0 + ml) * K + quad * 8;

    f32x4 acc[2][8];
#pragma unroll
    for (int i = 0; i < 2; ++i)
#pragma unroll
        for (int j = 0; j < 8; ++j) acc[i][j] = (f32x4){0.f, 0.f, 0.f, 0.f};

#pragma unroll 2
    for (int k0 = 0; k0 < K; k0 += 32) {
        f16x8 a0 = *(const f16x8*)(ap0 + k0);
        f16x8 a1 = *(const f16x8*)(ap1 + k0);
#pragma unroll
        for (int nf = 0; nf < 8; ++nf) {
            f16x8 bf = *(const f16x8*)(bp0 + (size_t)nf * 16 * K + k0);
            acc[0][nf] = __builtin_amdgcn_mfma_f32_16x16x32_f16(a0, bf, acc[0][nf], 0, 0, 0);
            acc[1][nf] = __builtin_amdgcn_mfma_f32_16x16x32_f16(a1, bf, acc[1][nf], 0, 0, 0);
        }
    }

#pragma unroll
    for (int mf = 0; mf < 2; ++mf)
#pragma unroll
        for (int nf = 0; nf < 8; ++nf) {
            const int col = n0 + nf * 16 + ml;
            const float bv = bias ? bias[col] : 0.f;
#pragma unroll
            for (int r = 0; r < 4; ++r) {
                const int row = m0 + mf * 16 + quad * 4 + r;
                float v = acc[mf][nf][r] + bv;
                if (F16OUT)
                    ((_Float16*)Cout)[(size_t)row * N + col] = (_Float16)v;
                else
                    ((float*)Cout)[(size_t)row * N + col] = v;
            }
        }
}

// ---------------------------------------------------------------------------
// GCN gather v3: Be precomputed by MFMA GEMM (R5: 320 us scalar -> off the
// top-5).  Edge loop: two loads + tanh + fma per feature.
// ---------------------------------------------------------------------------
__global__ __launch_bounds__(256) void k_gcn(const float* __restrict__ Ax,
                                             const _Float16* __restrict__ Be16,
                                             const int* __restrict__ ei,
                                             const int* __restrict__ eidx,
                                             const int* __restrict__ offs,
                                             const int* __restrict__ deg,
                                             const float* __restrict__ dinv,
                                             const float* __restrict__ Bself,
                                             const float* __restrict__ gcn_bias,
                                             _Float16* __restrict__ node16) {
    const int v = blockIdx.x;
    const int f = threadIdx.x;

    __shared__ int   es_s[ECAP];
    __shared__ int   src_s[ECAP];
    __shared__ float nrm_s[ECAP];

    const int   base = offs[v];
    const int   cnt  = deg[v];                   // raw in-edges
    const float dv   = dinv[v];
    float acc = 0.f;

    for (int c0 = 0; c0 < cnt; c0 += ECAP) {
        const int n = min(ECAP, cnt - c0);
        if (f < n) {
            int e = eidx[base + c0 + f];
            es_s[f] = e;
            int s = ei[e];
            src_s[f] = s;
            nrm_s[f] = dinv[s] * dv;
        }
        __syncthreads();
#pragma unroll 4
        for (int i = 0; i < n; ++i) {
            float ax = Ax[(size_t)src_s[i] * DOUT + f];
            float be = (float)Be16[(size_t)es_s[i] * DOUT + f];
            acc = fmaf(nrm_s[i], fast_tanh(ax * be), acc);
        }
        __syncthreads();                          // before chunk overwrite
    }
    // self loop: norm = dinv^2, Be = rowsum(WB)
    acc += dv * dv * fast_tanh(Ax[(size_t)v * DOUT + f] * Bself[f]);
    float nv = fast_tanh(acc / (float)(cnt + 1) + gcn_bias[f]);
    node16[(size_t)v * DOUT + f] = (_Float16)nv;
}

// ---------------------------------------------------------------------------
// GRU scan v15: TWO GRAPHS / BLOCK, ANTI-PHASED WAVE GROUPS.
//
// v12's step = 2823 cyc: MFMA issue ~1540-1860 + VALU gate-tail ~950 + sync.
// All 8 waves were phase-locked -> the tail ran with the matrix pipe idle.
// m114: MFMA-waves and VALU-waves on one CU co-schedule fully (max, not sum).
//
// v15: 1024 threads = 16 waves; waves 0-7 = graph A, 8-15 = graph B
// (2 A-waves + 2 B-waves per SIMD).  B is skewed half a step.  Region t:
//   half1: A: MFMA(t)        | B: gate-tail(t-1)  (writes h_B(t))
//   bar_lds()
//   half2: A: gate-tail(t)   | B: MFMA(t)
//   bar_lds()
// Each half's VALU tail hides under the other group's MFMA issue.  Per-wave
// math is byte-identical to v12 (wv->gw, LDS slot per graph, C[6] lives
// across one barrier).  All sync block-internal (v11's cross-CU mistake
// avoided).  Barriers are unconditional; divergence is wave-uniform.
// ---------------------------------------------------------------------------
#define GRU_MFMA(slot, t)                                                     \
  {                                                                           \
    const _Float16* hcur = h16[slot][(t) & 1];                                \
    _Pragma("unroll")                                                         \
    for (int rb = 0; rb < 6; ++rb) C[rb] = (f32x4){0.f, 0.f, 0.f, 0.f};       \
    _Pragma("unroll")                                                         \
    for (int kt = 0; kt < 8; ++kt) {                                          \
      union { f16x8 v; float4 f; } Bk;                                        \
      Bk.f = *(const float4*)&hcur[kt * 32 + quad * 8];                       \
      _Pragma("unroll")                                                       \
      for (int rb = 0; rb < 6; ++rb)                                          \
        C[rb] = __builtin_amdgcn_mfma_f32_16x16x32_f16(A[rb][kt], Bk.v,       \
                                                       C[rb], 0, 0, 0);       \
    }                                                                         \
  }

#define GRU_TAIL(s)                                                           \
  {                                                                           \
    const float xr = (float)pxr, xz = (float)pxz, xn = (float)pxn;            \
    {                                                                         \
      const _Float16* xq = xpb + (size_t)((s) + 1) * G3 + j;                  \
      pxr = xq[0]; pxz = xq[256]; pxn = xq[512];                              \
    }                                                                         \
    float gh[3];                                                              \
    _Pragma("unroll")                                                         \
    for (int g = 0; g < 3; ++g) {                                             \
      const float lo01 = (rsel & 1) ? C[2 * g][1] : C[2 * g][0];              \
      const float lo23 = (rsel & 1) ? C[2 * g][3] : C[2 * g][2];              \
      const float lo   = (rsel & 2) ? lo23 : lo01;                            \
      const float hi01 = (rsel & 1) ? C[2 * g + 1][1] : C[2 * g + 1][0];      \
      const float hi23 = (rsel & 1) ? C[2 * g + 1][3] : C[2 * g + 1][2];      \
      const float hi   = (rsel & 2) ? hi23 : hi01;                            \
      gh[g] = p ? hi : lo;                                                    \
    }                                                                         \
    const float r_ = fast_sigmoid(xr + gh[0]);                                \
    const float z_ = fast_sigmoid(xz + gh[1]);                                \
    const float n_ = fast_tanh(xn + r_ * (gh[2] + bhn));                      \
    const float hn = n_ + z_ * (h_old - n_);                                  \
    h_old = hn;                                                               \
    if (wr) {                                                                 \
      h16[gslot][((s) & 1) ^ 1][j] = (_Float16)hn;                            \
      if (layer < 2) {                                                        \
        yb16[(size_t)(s) * DOUT + j] = (_Float16)hn;                          \
        if ((s) == SEQT - 1) hT_all[layer * NB * 256 + b * 256 + j] = hn;     \
      }                                                                       \
    }                                                                         \
    if (layer == 2) { mx = fmaxf(mx, hn); sm += hn; }                         \
  }

__global__ __launch_bounds__(1024) void k_gru_scan(const _Float16* __restrict__ xp16,
                                                   const float* __restrict__ w_hh,
                                                   const float* __restrict__ b_hh,
                                                   _Float16* __restrict__ y16,
                                                   float* __restrict__ hT_all,
                                                   int layer,
                                                   const float* __restrict__ lin_W,
                                                   const float* __restrict__ lin_b,
                                                   float* __restrict__ out) {
    const int tid   = threadIdx.x;
    const int wv16  = tid >> 6;                  // 0..15
    const bool gA   = wv16 < 8;                  // wave-uniform group split
    const int gw    = wv16 & 7;                  // group-local wave 0..7
    const int gslot = gA ? 0 : 1;
    const int b     = blockIdx.x * 2 + gslot;    // this group's graph
    const int lane  = tid & 63;
    const int m     = lane & 15;
    const int quad  = lane >> 4;
    const int p     = (m >> 3) & 1;
    const int rsel  = m & 3;
    const int j     = gw * 32 + p * 16 + quad * 4 + rsel;
    const bool wr   = (m & 4) == 0;
    const int gtid  = tid & 511;                 // group-local tid

    // --- weights -> A-fragments (identical per group; same layer weights) ---
    f16x8 A[6][8];
#pragma unroll
    for (int rb = 0; rb < 6; ++rb) {
        const int lr  = rb * 16 + m;
        const int row = ((lr >> 5) << 8) + gw * 32 + (lr & 31);
#pragma unroll
        for (int kt = 0; kt < 8; ++kt) {
            const float* wp = w_hh + (size_t)row * 256 + kt * 32 + quad * 8;
            float4 a0 = *(const float4*)wp;
            float4 a1 = *(const float4*)(wp + 4);
            union { f16x8 v; h2_t h[4]; } u;
            u.h[0] = pk(a0.x, a0.y); u.h[1] = pk(a0.z, a0.w);
            u.h[2] = pk(a1.x, a1.y); u.h[3] = pk(a1.z, a1.w);
            A[rb][kt] = u.v;
        }
    }

    const float bhn = b_hh[512 + j];

    __shared__ _Float16 h16[2][2][256];          // [graph-slot][parity][j]
    __shared__ float    pool[2][1280];           // layer-2 epilogue
    __shared__ float    red[2][512];

    float h_old = 0.f;
    if (gtid < 256) h16[gslot][0][gtid] = (_Float16)0.f;
    __syncthreads();

    const _Float16* xpb  = xp16 + (size_t)b * SEQT * G3;
    _Float16*       yb16 = y16  + (size_t)b * SEQT * DOUT;

    float mx = -1e30f, sm = 0.f;
    _Float16 pxr = xpb[j], pxz = xpb[256 + j], pxn = xpb[512 + j];

    f32x4 C[6];
#pragma unroll
    for (int rb = 0; rb < 6; ++rb) C[rb] = (f32x4){0.f, 0.f, 0.f, 0.f};

    for (int t = 0; t < SEQT; ++t) {
        if (gA)        { GRU_MFMA(0, t); }
        else if (t > 0){ GRU_TAIL(t - 1); }
        bar_lds();                               // h_B(t) visible; C_A done
        if (gA)        { GRU_TAIL(t); }
        else           { GRU_MFMA(1, t); }
        bar_lds();                               // h_A(t+1) visible
    }
    if (!gA) { GRU_TAIL(SEQT - 1); }             // B's final half-step

    if (layer == 2) {
        // --- fused pooling + linear + softmax, per group ---
        if (wr) {
            pool[gslot][j]        = hT_all[b * 256 + j];            // l0 hT
            pool[gslot][256 + j]  = hT_all[NB * 256 + b * 256 + j]; // l1 hT
            pool[gslot][512 + j]  = h_old;                          // l2 hT
            pool[gslot][768 + j]  = mx;
            pool[gslot][1024 + j] = sm * (1.f / 256.f);
        }
        __syncthreads();
        if (gtid < 256) {
            float p0 = 0.f, p1 = 0.f;
            for (int i = gtid; i < 1280; i += 256) {
                float pv = pool[gslot][i];
                p0 = fmaf(lin_W[i], pv, p0);
                p1 = fmaf(lin_W[1280 + i], pv, p1);
            }
            red[gslot][gtid] = p0; red[gslot][256 + gtid] = p1;
        }
        __syncthreads();
        if (gtid == 0) {
            float l0 = lin_b[0], l1 = lin_b[1];
            for (int i = 0; i < 256; ++i) {
                l0 += red[gslot][i];
                l1 += red[gslot][256 + i];
            }
            float m2 = fmaxf(l0, l1);
            float e0 = __expf(l0 - m2), e1 = __expf(l1 - m2);
            float s = e0 + e1;
            out[b * 2 + 0] = e0 / s;
            out[b * 2 + 1] = e1 / s;
        }
    }
}

// ---------------------------------------------------------------------------
extern "C" void kernel_launch(void* const* d_in, const int* in_sizes, int n_in,
                              void* d_out, int out_size, void* d_ws, size_t ws_size,
                              hipStream_t stream) {
    const float* x         = (const float*)d_in[0];
    const float* edge_attr = (const float*)d_in[1];
    const int*   ei        = (const int*)d_in[2];
    const float* WA        = (const float*)d_in[3];
    const float* WB        = (const float*)d_in[4];
    const float* gcn_bias  = (const float*)d_in[5];
    const float* w_ih[3] = {(const float*)d_in[6],  (const float*)d_in[10], (const float*)d_in[14]};
    const float* w_hh[3] = {(const float*)d_in[7],  (const float*)d_in[11], (const float*)d_in[15]};
    const float* b_ih[3] = {(const float*)d_in[8],  (const float*)d_in[12], (const float*)d_in[16]};
    const float* b_hh[3] = {(const float*)d_in[9],  (const float*)d_in[13], (const float*)d_in[17]};
    const float* lin_W = (const float*)d_in[18];
    const float* lin_b = (const float*)d_in[19];
    float* out = (float*)d_out;

    char* p = (char*)d_ws;
    auto alloc = [&](size_t bytes) {
        char* r = p;
        p += (bytes + 255) & ~(size_t)255;
        return r;
    };
    int*   deg    = (int*)alloc((size_t)NN * 4);   // ┐ contiguous: one memset
    int*   offs   = (int*)alloc((size_t)NN * 4);   // │
    int*   cursor = (int*)alloc((size_t)NN * 4);   // ┘
    float* dinv   = (float*)alloc((size_t)NN * 4);
    int*   eidx   = (int*)alloc((size_t)NE * 4);
    float* Bself  = (float*)alloc(256 * 4);
    float* hT     = (float*)alloc(2 * NB * 256 * 4);
    float* bias768 = (float*)alloc(3 * G3 * 4);
    float* Ax     = (float*)alloc((size_t)NN * DOUT * 4);
    _Float16* xp16 = (_Float16*)alloc((size_t)NN * G3 * 2);

    _Float16* node16 = (_Float16*)alloc((size_t)NN * DOUT * 2);
    _Float16* yA16   = (_Float16*)alloc((size_t)NN * DOUT * 2);
    _Float16* x16    = (_Float16*)alloc((size_t)NN * DOUT * 2);
    _Float16* yB16   = x16;  // alias: x16 dead after Ax GEMM, yB16 live later
    _Float16* WA16   = (_Float16*)alloc((size_t)256 * 256 * 2);
    _Float16* wih16[3];
    for (int l = 0; l < 3; ++l) wih16[l] = (_Float16*)alloc((size_t)G3 * 256 * 2);
    _Float16* ea16 = (_Float16*)alloc((size_t)NE * DEP * 2);
    _Float16* WB16 = (_Float16*)alloc((size_t)256 * DEP * 2);
    _Float16* Be16 = (_Float16*)alloc((size_t)NE * DOUT * 2);

    // --- CSR build + weight conversions + bias fold ---
    hipMemsetAsync(deg, 0, (size_t)3 * NN * 4, stream);    // deg+offs+cursor
    k_count<<<NE / 256, 256, 0, stream>>>(ei, deg);
    k_scan_offs<<<1, 1024, 0, stream>>>(deg, offs, dinv);
    k_fill<<<NE / 256, 256, 0, stream>>>(ei, offs, cursor, eidx);
    k_prep<<<10, 256, 0, stream>>>(WB, Bself,
                                   b_ih[0], b_hh[0], b_ih[1], b_hh[1],
                                   b_ih[2], b_hh[2], bias768);
    // total f32->f16 elements: 4194304+65536+3*196608+16777216+16384 = 21643264
    k_cvt_all<<<21136, 256, 0, stream>>>(x, WA, w_ih[0], w_ih[1], w_ih[2],
                                         edge_attr, WB,
                                         x16, WA16, wih16[0], wih16[1], wih16[2],
                                         ea16, WB16);

    // --- GCN ---
    {
        dim3 g(NN / 128, 256 / 128);
        k_gemm16<256, false><<<g, 256, 0, stream>>>(x16, WA16, nullptr, Ax, NN, 256);
    }
    {   // Be[E,256] = ea[E,64] @ WB[256,64]^T  (MFMA, was scalar VALU in k_gcn)
        dim3 g(NE / 128, 256 / 128);
        k_gemm16<64, true><<<g, 256, 0, stream>>>(ea16, WB16, nullptr, Be16, NE, 256);
    }
    k_gcn<<<NN, 256, 0, stream>>>(Ax, Be16, ei, eidx, offs, deg, dinv,
                                  Bself, gcn_bias, node16);

    // --- GRU x3 (layer 2 fuses pooling+linear+softmax) ---
    const _Float16* in16 = node16;
    _Float16* y16_outs[3] = {yA16, yB16, yA16};
    for (int l = 0; l < 3; ++l) {
        dim3 g(NN / 128, G3 / 128);
        k_gemm16<256, true><<<g, 256, 0, stream>>>(in16, wih16[l], bias768 + l * G3,
                                                   xp16, NN, G3);
        k_gru_scan<<<NB / 2, 1024, 0, stream>>>(xp16, w_hh[l], b_hh[l], y16_outs[l],
                                                hT, l, lin_W, lin_b, out);
        in16 = y16_outs[l];
    }
}

// Round 9
// 1255.146 us; speedup vs baseline: 10.8077x; 10.8077x over previous
//
#include <hip/hip_runtime.h>
#include <math.h>

#define NN   16384      // total nodes
#define NE   262144     // edges (no self loops)
#define NB   64         // graphs
#define SEQT 256        // nodes per graph (= seq len)
#define DEP  64
#define DOUT 256        // = HID
#define G3   768        // 3*HID
#define ECAP 64         // GCN edges staged per chunk
#define CVTB 21136      // k_cvt blocks covering 21,643,264 f32->f16 elems

typedef _Float16 h2_t   __attribute__((ext_vector_type(2)));
typedef _Float16 f16x4  __attribute__((ext_vector_type(4)));
typedef _Float16 f16x8  __attribute__((ext_vector_type(8)));
typedef float    f32x4  __attribute__((ext_vector_type(4)));

static __device__ __forceinline__ h2_t pk(float a, float b) {
    return (h2_t)__builtin_amdgcn_cvt_pkrtz(a, b);
}

static __device__ __forceinline__ float fast_sigmoid(float v) {
    return __builtin_amdgcn_rcpf(1.f + __expf(-v));
}
static __device__ __forceinline__ float fast_tanh(float v) {
    return 1.f - 2.f * __builtin_amdgcn_rcpf(1.f + __expf(2.f * v));
}

// barrier with LDS-only drain (no vmcnt: in-flight global loads/stores cross)
static __device__ __forceinline__ void bar_lds() {
    asm volatile("s_waitcnt lgkmcnt(0)\n\ts_barrier" ::: "memory");
}

// ---------------------------------------------------------------------------
// degree / CSR build (deg zero-initialized by memset; holds RAW in-degree)
// ---------------------------------------------------------------------------
__global__ void k_count(const int* __restrict__ ei, int* deg) {
    int e = blockIdx.x * 256 + threadIdx.x;
    if (e < NE) atomicAdd(&deg[ei[NE + e]], 1);   // col = dst
}

__global__ __launch_bounds__(1024) void k_scan_offs(const int* __restrict__ deg,
                                                    int* __restrict__ offs,
                                                    float* __restrict__ dinv) {
    __shared__ int lds[1024];
    const int tid = threadIdx.x;
    const int v0 = tid * 16;
    int loc[16];
    int s = 0;
#pragma unroll
    for (int i = 0; i < 16; ++i) {
        int d = deg[v0 + i];                      // raw in-edges
        loc[i] = s;
        s += d;
        dinv[v0 + i] = rsqrtf((float)(d + 1));    // +1 self loop
    }
    lds[tid] = s;
    __syncthreads();
    for (int off = 1; off < 1024; off <<= 1) {
        int x = (tid >= off) ? lds[tid - off] : 0;
        __syncthreads();
        lds[tid] += x;
        __syncthreads();
    }
    int base = lds[tid] - s;                      // exclusive prefix of this thread
#pragma unroll
    for (int i = 0; i < 16; ++i) offs[v0 + i] = base + loc[i];
}

__global__ void k_fill(const int* __restrict__ ei, const int* __restrict__ offs,
                       int* cursor, int* __restrict__ eidx) {
    int e = blockIdx.x * 256 + threadIdx.x;
    if (e < NE) {
        int c = ei[NE + e];
        int pos = offs[c] + atomicAdd(&cursor[c], 1);
        eidx[pos] = e;
    }
}

// ---------------------------------------------------------------------------
// fused fp32->f16 conversion over all 7 regions + prep tail blocks:
// block CVTB   -> Bself (rowsum of WB)
// blocks CVTB+1..CVTB+9 -> bias fold: bias768[l][j] = b_ih[j] + (j<512?b_hh[j]:0)
// ---------------------------------------------------------------------------
__global__ void k_cvt_all(const float* __restrict__ x,  const float* __restrict__ wa,
                          const float* __restrict__ w0, const float* __restrict__ w1,
                          const float* __restrict__ w2, const float* __restrict__ ea,
                          const float* __restrict__ wb,
                          _Float16* __restrict__ xo,  _Float16* __restrict__ wao,
                          _Float16* __restrict__ w0o, _Float16* __restrict__ w1o,
                          _Float16* __restrict__ w2o, _Float16* __restrict__ eao,
                          _Float16* __restrict__ wbo,
                          float* __restrict__ Bself,
                          const float* __restrict__ bi0, const float* __restrict__ bh0,
                          const float* __restrict__ bi1, const float* __restrict__ bh1,
                          const float* __restrict__ bi2, const float* __restrict__ bh2,
                          float* __restrict__ bias768) {
    if (blockIdx.x >= CVTB) {                   // prep tail
        const int pb = blockIdx.x - CVTB;
        if (pb == 0) {
            int f = threadIdx.x;                  // 256 threads
            float s = 0.f;
#pragma unroll
            for (int d = 0; d < DEP; ++d) s += wb[f * DEP + d];
            Bself[f] = s;
            return;
        }
        int j = (pb - 1) * 256 + threadIdx.x;     // 9 blocks x 256 = 2304
        int l = j / G3, r = j % G3;
        const float* bi = (l == 0) ? bi0 : (l == 1) ? bi1 : bi2;
        const float* bh = (l == 0) ? bh0 : (l == 1) ? bh1 : bh2;
        bias768[j] = bi[r] + (r < 512 ? bh[r] : 0.f);
        return;
    }
    size_t i = ((size_t)blockIdx.x * 256 + threadIdx.x) * 4;
    const size_t B0 = 4194304;                  // x: NN*256
    const size_t B1 = B0 + 65536;               // WA: 256*256
    const size_t B2 = B1 + 196608;              // w_ih0: 768*256
    const size_t B3 = B2 + 196608;              // w_ih1
    const size_t B4 = B3 + 196608;              // w_ih2
    const size_t B5 = B4 + 16777216;            // edge_attr: NE*64
    const float* in; _Float16* out; size_t off;
    if      (i < B0) { in = x;  out = xo;  off = i; }
    else if (i < B1) { in = wa; out = wao; off = i - B0; }
    else if (i < B2) { in = w0; out = w0o; off = i - B1; }
    else if (i < B3) { in = w1; out = w1o; off = i - B2; }
    else if (i < B4) { in = w2; out = w2o; off = i - B3; }
    else if (i < B5) { in = ea; out = eao; off = i - B4; }
    else             { in = wb; out = wbo; off = i - B5; }
    float4 v = *(const float4*)(in + off);
    *(h2_t*)(out + off)     = pk(v.x, v.y);
    *(h2_t*)(out + off + 2) = pk(v.z, v.w);
}

// ---------------------------------------------------------------------------
// MFMA f16 GEMM: C[M,N] = A16[M,K] @ B16[N,K]^T (+ bias).
// K: 256 (node GEMMs) or 64 (edge Be GEMM). F16OUT: f16 store, else fp32.
// ---------------------------------------------------------------------------
template <int K, bool F16OUT>
__global__ __launch_bounds__(256) void k_gemm16(const _Float16* __restrict__ A16,
                                                const _Float16* __restrict__ B16,
                                                const float* __restrict__ bias,
                                                void* __restrict__ Cout,
                                                int M, int N) {
    const int tid  = threadIdx.x;
    const int lane = tid & 63;
    const int wv   = tid >> 6;
    const int m0   = blockIdx.x * 128 + wv * 32;
    const int n0   = blockIdx.y * 128;
    const int ml   = lane & 15;
    const int quad = lane >> 4;

    const _Float16* ap0 = A16 + (size_t)(m0 + ml) * K + quad * 8;
    const _Float16* ap1 = ap0 + (size_t)16 * K;
    const _Float16* bp0 = B16 + (size_t)(n0 + ml) * K + quad * 8;

    f32x4 acc[2][8];
#pragma unroll
    for (int i = 0; i < 2; ++i)
#pragma unroll
        for (int j = 0; j < 8; ++j) acc[i][j] = (f32x4){0.f, 0.f, 0.f, 0.f};

#pragma unroll 2
    for (int k0 = 0; k0 < K; k0 += 32) {
        f16x8 a0 = *(const f16x8*)(ap0 + k0);
        f16x8 a1 = *(const f16x8*)(ap1 + k0);
#pragma unroll
        for (int nf = 0; nf < 8; ++nf) {
            f16x8 bf = *(const f16x8*)(bp0 + (size_t)nf * 16 * K + k0);
            acc[0][nf] = __builtin_amdgcn_mfma_f32_16x16x32_f16(a0, bf, acc[0][nf], 0, 0, 0);
            acc[1][nf] = __builtin_amdgcn_mfma_f32_16x16x32_f16(a1, bf, acc[1][nf], 0, 0, 0);
        }
    }

#pragma unroll
    for (int mf = 0; mf < 2; ++mf)
#pragma unroll
        for (int nf = 0; nf < 8; ++nf) {
            const int col = n0 + nf * 16 + ml;
            const float bv = bias ? bias[col] : 0.f;
#pragma unroll
            for (int r = 0; r < 4; ++r) {
                const int row = m0 + mf * 16 + quad * 4 + r;
                float v = acc[mf][nf][r] + bv;
                if (F16OUT)
                    ((_Float16*)Cout)[(size_t)row * N + col] = (_Float16)v;
                else
                    ((float*)Cout)[(size_t)row * N + col] = v;
            }
        }
}

// ---------------------------------------------------------------------------
// GCN gather v3: Be precomputed by MFMA GEMM (R5: 320 us scalar -> off the
// top-5).  Edge loop: two loads + tanh + fma per feature.
// ---------------------------------------------------------------------------
__global__ __launch_bounds__(256) void k_gcn(const float* __restrict__ Ax,
                                             const _Float16* __restrict__ Be16,
                                             const int* __restrict__ ei,
                                             const int* __restrict__ eidx,
                                             const int* __restrict__ offs,
                                             const int* __restrict__ deg,
                                             const float* __restrict__ dinv,
                                             const float* __restrict__ Bself,
                                             const float* __restrict__ gcn_bias,
                                             _Float16* __restrict__ node16) {
    const int v = blockIdx.x;
    const int f = threadIdx.x;

    __shared__ int   es_s[ECAP];
    __shared__ int   src_s[ECAP];
    __shared__ float nrm_s[ECAP];

    const int   base = offs[v];
    const int   cnt  = deg[v];                   // raw in-edges
    const float dv   = dinv[v];
    float acc = 0.f;

    for (int c0 = 0; c0 < cnt; c0 += ECAP) {
        const int n = min(ECAP, cnt - c0);
        if (f < n) {
            int e = eidx[base + c0 + f];
            es_s[f] = e;
            int s = ei[e];
            src_s[f] = s;
            nrm_s[f] = dinv[s] * dv;
        }
        __syncthreads();
#pragma unroll 4
        for (int i = 0; i < n; ++i) {
            float ax = Ax[(size_t)src_s[i] * DOUT + f];
            float be = (float)Be16[(size_t)es_s[i] * DOUT + f];
            acc = fmaf(nrm_s[i], fast_tanh(ax * be), acc);
        }
        __syncthreads();                          // before chunk overwrite
    }
    // self loop: norm = dinv^2, Be = rowsum(WB)
    acc += dv * dv * fast_tanh(Ax[(size_t)v * DOUT + f] * Bself[f]);
    float nv = fast_tanh(acc / (float)(cnt + 1) + gcn_bias[f]);
    node16[(size_t)v * DOUT + f] = (_Float16)nv;
}

// ---------------------------------------------------------------------------
// GRU scan v12 (RESTORED -- proven 298 us/dispatch, R7): kt-outer MFMA
// (6 independent chains) + fully in-register gates, 1 barrier/step.
//
// Structural map (measured):
//  - v11 cross-block row-split: cross-CU per-step sync ~20k cyc -> 6x loss.
//  - v15 anti-phase 16-wave block: 128-reg/wave budget < 192-reg A-frags ->
//    full scratch spill (VGPR_Count 64, WRITE_SIZE 2.4x) -> 14x loss.
//  - v14 gate-pair-major: 2 chains stall on MFMA latency -> -3%.
//  => per-step chain MFMA -> gates -> h-publish is serial by recurrence;
//     pipes measured 1537 (MFMA) + 937 (VALU) of 2790 cyc.  This structure
//     is the practical f16 floor.
// ---------------------------------------------------------------------------
__global__ __launch_bounds__(512, 2) void k_gru_scan(const _Float16* __restrict__ xp16,
                                                     const float* __restrict__ w_hh,
                                                     const float* __restrict__ b_hh,
                                                     _Float16* __restrict__ y16,
                                                     float* __restrict__ hT_all,
                                                     int layer,
                                                     const float* __restrict__ lin_W,
                                                     const float* __restrict__ lin_b,
                                                     float* __restrict__ out) {
    const int tid  = threadIdx.x;
    const int b    = blockIdx.x;                 // graph
    const int lane = tid & 63;
    const int wv   = tid >> 6;                   // wave 0..7
    const int m    = lane & 15;                  // A-frag row within 16
    const int quad = lane >> 4;                  // 0..3 (k-subgroup)
    const int p    = (m >> 3) & 1;               // frag-half select
    const int rsel = m & 3;                      // C-reg select
    const int j    = wv * 32 + p * 16 + quad * 4 + rsel;  // lane's hidden unit
    const bool wr  = (m & 4) == 0;               // unique writer per j (2 lanes/j)

    // --- weights -> A-fragments (one-time global read, fp32 -> f16) ---
    // local row lr = rb*16 + m; global w_hh row = 256*(lr/32) + 32*wv + lr%32
    // => frag pair (2g, 2g+1) holds gate g's rows for this wave's 32 j's.
    f16x8 A[6][8];
#pragma unroll
    for (int rb = 0; rb < 6; ++rb) {
        const int lr  = rb * 16 + m;
        const int row = ((lr >> 5) << 8) + wv * 32 + (lr & 31);
#pragma unroll
        for (int kt = 0; kt < 8; ++kt) {
            const float* wp = w_hh + (size_t)row * 256 + kt * 32 + quad * 8;
            float4 a0 = *(const float4*)wp;
            float4 a1 = *(const float4*)(wp + 4);
            union { f16x8 v; h2_t h[4]; } u;
            u.h[0] = pk(a0.x, a0.y); u.h[1] = pk(a0.z, a0.w);
            u.h[2] = pk(a1.x, a1.y); u.h[3] = pk(a1.z, a1.w);
            A[rb][kt] = u.v;
        }
    }

    const float bhn = b_hh[512 + j];             // n-gate hidden bias (r/z folded)

    __shared__ _Float16 h16[2][256];             // h(t) f16, double-buffered
    __shared__ float    pool[1280];              // layer-2 epilogue only
    __shared__ float    red[512];

    float h_old = 0.f;                           // this lane's h[j]
    if (tid < 256) h16[0][tid] = (_Float16)0.f;
    __syncthreads();

    const _Float16* xpb  = xp16 + (size_t)b * SEQT * G3;
    _Float16*       yb16 = y16  + (size_t)b * SEQT * DOUT;

    float mx = -1e30f, sm = 0.f;                 // layer-2 pooling accum

    // prefetch xp(0) (loop-carried registers; re-issued each step for t+1)
    _Float16 pxr = xpb[j], pxz = xpb[256 + j], pxn = xpb[512 + j];

    for (int t = 0; t < SEQT; ++t) {
        // consume this step's prefetched xp (loads issued one step ago)
        const float xr = (float)pxr;
        const float xz = (float)pxz;
        const float xn = (float)pxn;
        // issue NEXT step's xp loads now -- they ride out the whole MFMA
        // phase + barrier (bar_lds has no vmcnt drain).  t=255 reads the
        // workspace tail: in-bounds, values unused.
        {
            const _Float16* xq = xpb + (size_t)(t + 1) * G3 + j;
            pxr = xq[0]; pxz = xq[256]; pxn = xq[512];
        }

        // k-outer MFMA: straight-line; compiler hoists the 8 ds_read_b128
        const _Float16* hcur = h16[t & 1];
        f32x4 C[6];
#pragma unroll
        for (int rb = 0; rb < 6; ++rb) C[rb] = (f32x4){0.f, 0.f, 0.f, 0.f};

#pragma unroll
        for (int kt = 0; kt < 8; ++kt) {
            union { f16x8 v; float4 f; } Bk;
            Bk.f = *(const float4*)&hcur[kt * 32 + quad * 8];
#pragma unroll
            for (int rb = 0; rb < 6; ++rb)
                C[rb] = __builtin_amdgcn_mfma_f32_16x16x32_f16(A[rb][kt], Bk.v, C[rb], 0, 0, 0);
        }

        // in-register gh extraction: value for this lane's j sits at
        // C[2g + p][rsel] (predicates rsel&1, rsel&2, p are loop-invariant)
        float gh[3];
#pragma unroll
        for (int g = 0; g < 3; ++g) {
            const float lo01 = (rsel & 1) ? C[2 * g][1] : C[2 * g][0];
            const float lo23 = (rsel & 1) ? C[2 * g][3] : C[2 * g][2];
            const float lo   = (rsel & 2) ? lo23 : lo01;
            const float hi01 = (rsel & 1) ? C[2 * g + 1][1] : C[2 * g + 1][0];
            const float hi23 = (rsel & 1) ? C[2 * g + 1][3] : C[2 * g + 1][2];
            const float hi   = (rsel & 2) ? hi23 : hi01;
            gh[g] = p ? hi : lo;
        }

        const float r  = fast_sigmoid(xr + gh[0]);
        const float z  = fast_sigmoid(xz + gh[1]);
        const float n  = fast_tanh(xn + r * (gh[2] + bhn));
        const float hn = n + z * (h_old - n);
        h_old = hn;
        if (wr) {
            h16[(t & 1) ^ 1][j] = (_Float16)hn;  // next step's buffer
            if (layer < 2) {
                yb16[(size_t)t * DOUT + j] = (_Float16)hn;
                if (t == SEQT - 1) hT_all[layer * NB * 256 + b * 256 + j] = hn;
            }
        }
        if (layer == 2) { mx = fmaxf(mx, hn); sm += hn; }

        bar_lds();                               // the ONLY per-step barrier
    }

    if (layer == 2) {
        // --- fused pooling + linear + softmax ---
        if (wr) {
            pool[j]        = hT_all[b * 256 + j];               // layer-0 hT
            pool[256 + j]  = hT_all[NB * 256 + b * 256 + j];    // layer-1 hT
            pool[512 + j]  = h_old;                             // layer-2 hT
            pool[768 + j]  = mx;
            pool[1024 + j] = sm * (1.f / 256.f);
        }
        __syncthreads();
        if (tid < 256) {
            float p0 = 0.f, p1 = 0.f;
            for (int i = tid; i < 1280; i += 256) {
                float pv = pool[i];
                p0 = fmaf(lin_W[i], pv, p0);
                p1 = fmaf(lin_W[1280 + i], pv, p1);
            }
            red[tid] = p0; red[256 + tid] = p1;
        }
        __syncthreads();
        if (tid == 0) {
            float l0 = lin_b[0], l1 = lin_b[1];
            for (int i = 0; i < 256; ++i) { l0 += red[i]; l1 += red[256 + i]; }
            float m2 = fmaxf(l0, l1);
            float e0 = __expf(l0 - m2), e1 = __expf(l1 - m2);
            float s = e0 + e1;
            out[b * 2 + 0] = e0 / s;
            out[b * 2 + 1] = e1 / s;
        }
    }
}

// ---------------------------------------------------------------------------
extern "C" void kernel_launch(void* const* d_in, const int* in_sizes, int n_in,
                              void* d_out, int out_size, void* d_ws, size_t ws_size,
                              hipStream_t stream) {
    const float* x         = (const float*)d_in[0];
    const float* edge_attr = (const float*)d_in[1];
    const int*   ei        = (const int*)d_in[2];
    const float* WA        = (const float*)d_in[3];
    const float* WB        = (const float*)d_in[4];
    const float* gcn_bias  = (const float*)d_in[5];
    const float* w_ih[3] = {(const float*)d_in[6],  (const float*)d_in[10], (const float*)d_in[14]};
    const float* w_hh[3] = {(const float*)d_in[7],  (const float*)d_in[11], (const float*)d_in[15]};
    const float* b_ih[3] = {(const float*)d_in[8],  (const float*)d_in[12], (const float*)d_in[16]};
    const float* b_hh[3] = {(const float*)d_in[9],  (const float*)d_in[13], (const float*)d_in[17]};
    const float* lin_W = (const float*)d_in[18];
    const float* lin_b = (const float*)d_in[19];
    float* out = (float*)d_out;

    char* p = (char*)d_ws;
    auto alloc = [&](size_t bytes) {
        char* r = p;
        p += (bytes + 255) & ~(size_t)255;
        return r;
    };
    int*   deg    = (int*)alloc((size_t)NN * 4);   // ┐ contiguous: one memset
    int*   offs   = (int*)alloc((size_t)NN * 4);   // │
    int*   cursor = (int*)alloc((size_t)NN * 4);   // ┘
    float* dinv   = (float*)alloc((size_t)NN * 4);
    int*   eidx   = (int*)alloc((size_t)NE * 4);
    float* Bself  = (float*)alloc(256 * 4);
    float* hT     = (float*)alloc(2 * NB * 256 * 4);
    float* bias768 = (float*)alloc(3 * G3 * 4);
    float* Ax     = (float*)alloc((size_t)NN * DOUT * 4);
    _Float16* xp16 = (_Float16*)alloc((size_t)NN * G3 * 2);

    _Float16* node16 = (_Float16*)alloc((size_t)NN * DOUT * 2);
    _Float16* yA16   = (_Float16*)alloc((size_t)NN * DOUT * 2);
    _Float16* x16    = (_Float16*)alloc((size_t)NN * DOUT * 2);
    _Float16* yB16   = x16;  // alias: x16 dead after Ax GEMM, yB16 live later
    _Float16* WA16   = (_Float16*)alloc((size_t)256 * 256 * 2);
    _Float16* wih16[3];
    for (int l = 0; l < 3; ++l) wih16[l] = (_Float16*)alloc((size_t)G3 * 256 * 2);
    _Float16* ea16 = (_Float16*)alloc((size_t)NE * DEP * 2);
    _Float16* WB16 = (_Float16*)alloc((size_t)256 * DEP * 2);
    _Float16* Be16 = (_Float16*)alloc((size_t)NE * DOUT * 2);

    // --- CSR build + fused conversions/prep ---
    hipMemsetAsync(deg, 0, (size_t)3 * NN * 4, stream);    // deg+offs+cursor
    k_count<<<NE / 256, 256, 0, stream>>>(ei, deg);
    k_scan_offs<<<1, 1024, 0, stream>>>(deg, offs, dinv);
    k_fill<<<NE / 256, 256, 0, stream>>>(ei, offs, cursor, eidx);
    // cvt (21136 blocks) + prep tail (10 blocks: Bself + bias fold)
    k_cvt_all<<<CVTB + 10, 256, 0, stream>>>(x, WA, w_ih[0], w_ih[1], w_ih[2],
                                             edge_attr, WB,
                                             x16, WA16, wih16[0], wih16[1], wih16[2],
                                             ea16, WB16,
                                             Bself,
                                             b_ih[0], b_hh[0], b_ih[1], b_hh[1],
                                             b_ih[2], b_hh[2], bias768);

    // --- GCN ---
    {
        dim3 g(NN / 128, 256 / 128);
        k_gemm16<256, false><<<g, 256, 0, stream>>>(x16, WA16, nullptr, Ax, NN, 256);
    }
    {   // Be[E,256] = ea[E,64] @ WB[256,64]^T  (MFMA, was scalar VALU in k_gcn)
        dim3 g(NE / 128, 256 / 128);
        k_gemm16<64, true><<<g, 256, 0, stream>>>(ea16, WB16, nullptr, Be16, NE, 256);
    }
    k_gcn<<<NN, 256, 0, stream>>>(Ax, Be16, ei, eidx, offs, deg, dinv,
                                  Bself, gcn_bias, node16);

    // --- GRU x3 (layer 2 fuses pooling+linear+softmax) ---
    const _Float16* in16 = node16;
    _Float16* y16_outs[3] = {yA16, yB16, yA16};
    for (int l = 0; l < 3; ++l) {
        dim3 g(NN / 128, G3 / 128);
        k_gemm16<256, true><<<g, 256, 0, stream>>>(in16, wih16[l], bias768 + l * G3,
                                                   xp16, NN, G3);
        k_gru_scan<<<NB, 512, 0, stream>>>(xp16, w_hh[l], b_hh[l], y16_outs[l],
                                           hT, l, lin_W, lin_b, out);
        in16 = y16_outs[l];
    }
}